// Round 4
// baseline (90.782 us; speedup 1.0000x reference)
//
#include <hip/hip_runtime.h>

#define D_   256
#define R_   128
#define NROW 4096            // B*K
#define TOPK 12
#define ROWS 4               // rows per main block
#define NBLK_MAIN (NROW / ROWS)   // 1024
#define INVSQRT2 0.70710678f

typedef _Float16 h2 __attribute__((ext_vector_type(2)));

__device__ __forceinline__ h2 bch2(unsigned u) { return __builtin_bit_cast(h2, u); }
__device__ __forceinline__ unsigned bcu(h2 h)  { return __builtin_bit_cast(unsigned, h); }
__device__ __forceinline__ unsigned splat2(float x) { h2 r; r.x = (_Float16)x; r.y = r.x; return bcu(r); }
__device__ __forceinline__ unsigned pack2(float a, float b) { h2 r; r.x = (_Float16)a; r.y = (_Float16)b; return bcu(r); }

struct GeluC { unsigned lo, hi, c6, c5, c4, c3, c2, c1, c0, is2; };

// acc += gelu(k + hr) * w, all packed f16x2, guaranteed v_pk_* via asm.
// gelu(x) = 0.5*x*(1+erf(x/sqrt2)); inputs are pre-scaled u = x/sqrt2.
// erf via deg-13 odd Taylor, clamped at |u|=1.45.
__device__ __forceinline__ void gelu_acc(unsigned& acc, unsigned k, unsigned hr,
                                         unsigned w, const GeluC& C) {
    unsigned u, uc, s, p;
    asm("v_pk_add_f16 %1, %5, %6\n\t"      // u = k + hr
        "v_pk_max_f16 %2, %1, %7\n\t"      // uc = max(u, lo)
        "v_pk_min_f16 %2, %2, %8\n\t"      // uc = min(uc, hi)
        "v_pk_mul_f16 %3, %2, %2\n\t"      // s = uc*uc
        "v_pk_fma_f16 %4, %9, %3, %10\n\t" // p = c6*s + c5
        "v_pk_fma_f16 %4, %4, %3, %11\n\t" // p = p*s + c4
        "v_pk_fma_f16 %4, %4, %3, %12\n\t" // c3
        "v_pk_fma_f16 %4, %4, %3, %13\n\t" // c2
        "v_pk_fma_f16 %4, %4, %3, %14\n\t" // c1
        "v_pk_fma_f16 %4, %4, %3, %15\n\t" // c0
        "v_pk_mul_f16 %2, %2, %4\n\t"      // erfv = uc*p
        "v_pk_mul_f16 %1, %1, %16\n\t"     // v = u*invsqrt2 (= 0.5x)
        "v_pk_fma_f16 %2, %1, %2, %1\n\t"  // g = v*erfv + v
        "v_pk_fma_f16 %0, %2, %17, %0"     // acc += g*w
        : "+v"(acc), "=&v"(u), "=&v"(uc), "=&v"(s), "=&v"(p)
        : "v"(k), "v"(hr), "v"(C.lo), "v"(C.hi), "v"(C.c6), "v"(C.c5),
          "v"(C.c4), "v"(C.c3), "v"(C.c2), "v"(C.c1), "v"(C.c0),
          "v"(C.is2), "v"(w));
}

// K1: hrbq[f4][r] = packed f16x4 of (receptors[r,:]@W1[D:,4f4..] + b1)/sqrt2
//     + recT[d][r] = receptors[r][d] (f32 transpose for phase F)
__global__ __launch_bounds__(256) void hrb_kernel(
    const float* __restrict__ receptors, const float* __restrict__ W1,
    const float* __restrict__ b1, uint2* __restrict__ hrbq,
    float* __restrict__ recT)
{
    __shared__ float tmp[D_];
    const int r = blockIdx.x;      // 0..127
    const int f = threadIdx.x;     // 0..255
    const float* wb = W1 + D_ * D_;
    float acc = 0.f;
    #pragma unroll 4
    for (int d = 0; d < D_; d++)
        acc = fmaf(receptors[r * D_ + d], wb[d * D_ + f], acc);
    tmp[f] = (acc + b1[f]) * INVSQRT2;
    recT[f * R_ + r] = receptors[r * D_ + f];
    __syncthreads();
    if (f < 64) {
        hrbq[f * R_ + r] = make_uint2(pack2(tmp[4 * f + 0], tmp[4 * f + 1]),
                                      pack2(tmp[4 * f + 2], tmp[4 * f + 3]));
    }
}

// K2: hkq[row][f4] = packed f16x4 of (keys @ W1[:D]) / sqrt2
__global__ __launch_bounds__(256) void hk_gemm(
    const float* __restrict__ keys, const float* __restrict__ W1,
    uint2* __restrict__ hkq)
{
    __shared__ float At[16][64];
    __shared__ float Bs[16][64];
    const int bx = blockIdx.x & 3;
    const int by = blockIdx.x >> 2;
    const int t  = threadIdx.x;
    const int tx = t & 15, ty = t >> 4;
    const int arow = t >> 2, akq = t & 3;
    const int bkr  = t >> 4, bnc = t & 15;
    const float* Aptr = keys + (by * 64 + arow) * D_;
    const int bcol = bx * 64 + bnc * 4;

    float acc[4][4] = {};
    float4 av = *(const float4*)(Aptr + akq * 4);
    float4 bv = *(const float4*)(W1 + bkr * D_ + bcol);
    for (int k0 = 0; k0 < 256; k0 += 16) {
        __syncthreads();
        At[akq * 4 + 0][arow] = av.x;
        At[akq * 4 + 1][arow] = av.y;
        At[akq * 4 + 2][arow] = av.z;
        At[akq * 4 + 3][arow] = av.w;
        *(float4*)&Bs[bkr][bnc * 4] = bv;
        __syncthreads();
        if (k0 + 16 < 256) {
            av = *(const float4*)(Aptr + k0 + 16 + akq * 4);
            bv = *(const float4*)(W1 + (k0 + 16 + bkr) * D_ + bcol);
        }
        #pragma unroll
        for (int kk = 0; kk < 16; kk++) {
            float4 a4 = *(const float4*)&At[kk][ty * 4];
            float4 b4 = *(const float4*)&Bs[kk][tx * 4];
            acc[0][0] = fmaf(a4.x, b4.x, acc[0][0]);
            acc[0][1] = fmaf(a4.x, b4.y, acc[0][1]);
            acc[0][2] = fmaf(a4.x, b4.z, acc[0][2]);
            acc[0][3] = fmaf(a4.x, b4.w, acc[0][3]);
            acc[1][0] = fmaf(a4.y, b4.x, acc[1][0]);
            acc[1][1] = fmaf(a4.y, b4.y, acc[1][1]);
            acc[1][2] = fmaf(a4.y, b4.z, acc[1][2]);
            acc[1][3] = fmaf(a4.y, b4.w, acc[1][3]);
            acc[2][0] = fmaf(a4.z, b4.x, acc[2][0]);
            acc[2][1] = fmaf(a4.z, b4.y, acc[2][1]);
            acc[2][2] = fmaf(a4.z, b4.z, acc[2][2]);
            acc[2][3] = fmaf(a4.z, b4.w, acc[2][3]);
            acc[3][0] = fmaf(a4.w, b4.x, acc[3][0]);
            acc[3][1] = fmaf(a4.w, b4.y, acc[3][1]);
            acc[3][2] = fmaf(a4.w, b4.z, acc[3][2]);
            acc[3][3] = fmaf(a4.w, b4.w, acc[3][3]);
        }
    }
    #pragma unroll
    for (int i = 0; i < 4; i++) {
        hkq[(by * 64 + ty * 4 + i) * 64 + bx * 16 + tx] =
            make_uint2(pack2(acc[i][0] * INVSQRT2, acc[i][1] * INVSQRT2),
                       pack2(acc[i][2] * INVSQRT2, acc[i][3] * INVSQRT2));
    }
}

// K3: fused main kernel. One block = 4 rows, 512 threads (8 waves).
__global__ __launch_bounds__(512, 8) void main_kernel(
    const float* __restrict__ keys, const float* __restrict__ recT,
    const float* __restrict__ W2,   const float* __restrict__ b2p,
    const float* __restrict__ scalep,
    const uint2* __restrict__ hkq,  const uint2* __restrict__ hrbq,
    float* __restrict__ out, float* __restrict__ partials)
{
    __shared__ uint2 hkl[ROWS][64];          // 2 KB
    __shared__ uint2 w2l[64];                // 0.5 KB
    __shared__ float part_lds[ROWS][2][R_];  // 4 KB
    __shared__ float bind_lds[ROWS][R_];     // 2 KB
    __shared__ float redS[ROWS], redN[ROWS];
    __shared__ float redX[ROWS][8];
    __shared__ float redV[2][8];

    const int t    = threadIdx.x;
    const int blk  = blockIdx.x;
    const int rowg = blk * ROWS;

    if (t < ROWS * 64) {
        hkl[t >> 6][t & 63] = hkq[rowg * 64 + t];
    } else if (t < ROWS * 64 + 64) {
        int f = t - ROWS * 64;
        w2l[f] = make_uint2(pack2(W2[4 * f + 0], W2[4 * f + 1]),
                            pack2(W2[4 * f + 2], W2[4 * f + 3]));
    }
    __syncthreads();

    const int r    = t & 127;
    const int part = t >> 7;          // 0..3
    const int rp   = part >> 1;       // row pair: rows 2rp, 2rp+1
    const int fh   = part & 1;        // f half
    const int f4b  = fh * 32;

    // ---- Phase B: affinity partials, fully packed f16 via asm ----
    const GeluC C = { splat2(-1.45f), splat2(1.45f),
                      splat2(1.2055333e-4f), splat2(-8.5483270e-4f),
                      splat2(5.2239776e-3f), splat2(-2.6866171e-2f),
                      splat2(1.1283792e-1f), splat2(-3.7612639e-1f),
                      splat2(1.1283792f),    splat2(INVSQRT2) };
    unsigned acc00 = 0u, acc01 = 0u, acc10 = 0u, acc11 = 0u;
    #pragma unroll 4
    for (int f4 = f4b; f4 < f4b + 32; ++f4) {
        uint2 hq = hrbq[f4 * R_ + r];           // coalesced 8B, L2-hot
        uint2 ka = hkl[2 * rp + 0][f4];         // LDS broadcast
        uint2 kb = hkl[2 * rp + 1][f4];
        uint2 wq = w2l[f4];
        gelu_acc(acc00, ka.x, hq.x, wq.x, C);
        gelu_acc(acc01, ka.y, hq.y, wq.y, C);
        gelu_acc(acc10, kb.x, hq.x, wq.x, C);
        gelu_acc(acc11, kb.y, hq.y, wq.y, C);
    }
    {
        h2 a0 = bch2(acc00), a1 = bch2(acc01), b0 = bch2(acc10), b1 = bch2(acc11);
        part_lds[2 * rp + 0][fh][r] = (float)a0.x + (float)a0.y + (float)a1.x + (float)a1.y;
        part_lds[2 * rp + 1][fh][r] = (float)b0.x + (float)b0.y + (float)b1.x + (float)b1.y;
    }
    __syncthreads();

    // ---- Phase C/D: wave-per-row; ballot-bisection top-12 threshold;
    //      in-wave softmax + stats. Waves 0..3 only (rows 0..3). ----
    const int w    = t >> 6;
    const int lane = t & 63;
    if (w < ROWS) {
        const int crow = w;
        float2 p0 = *(const float2*)&part_lds[crow][0][2 * lane];
        float2 p1 = *(const float2*)&part_lds[crow][1][2 * lane];
        const float b2 = b2p[0];
        float a0 = p0.x + p1.x + b2;
        float a1 = p0.y + p1.y + b2;

        float mx = fmaxf(a0, a1), mn = fminf(a0, a1);
        #pragma unroll
        for (int o = 32; o > 0; o >>= 1) {
            mx = fmaxf(mx, __shfl_xor(mx, o, 64));
            mn = fminf(mn, __shfl_xor(mn, o, 64));
        }
        float lo = mn - 1e-3f, hi = mx + 1e-3f;
        #pragma unroll 4
        for (int it = 0; it < 24; ++it) {
            float mid = 0.5f * (lo + hi);
            int c = __popcll(__ballot(a0 > mid)) + __popcll(__ballot(a1 > mid));
            if (c >= TOPK) lo = mid; else hi = mid;
        }
        const float thr = lo;

        float e0 = __expf(a0 - mx), e1 = __expf(a1 - mx);
        float s = e0 + e1;
        #pragma unroll
        for (int o = 32; o > 0; o >>= 1) s += __shfl_xor(s, o, 64);
        const float inv_den = 1.0f / s;
        const float sg0 = 1.0f / (1.0f + __expf(-10.0f * (a0 - thr)));
        const float sg1 = 1.0f / (1.0f + __expf(-10.0f * (a1 - thr)));
        const float b0 = e0 * inv_den * sg0;
        const float b1 = e1 * inv_den * sg1;
        *(float2*)&bind_lds[crow][2 * lane] = make_float2(b0, b1);
        float q = b0 * b0 + b1 * b1;
        float n = b0 * __logf(b0 + 1e-8f) + b1 * __logf(b1 + 1e-8f);
        #pragma unroll
        for (int o = 32; o > 0; o >>= 1) {
            q += __shfl_xor(q, o, 64);
            n += __shfl_xor(n, o, 64);
        }
        if (lane == 0) { redS[crow] = q; redN[crow] = n; }
    }
    __syncthreads();

    if (t == 0) {
        partials[blk * 4 + 0] = redS[0] + redS[1] + redS[2] + redS[3];
        partials[blk * 4 + 1] = redN[0] + redN[1] + redN[2] + redN[3];
    }

    // ---- Phase F: bound = binding @ receptors; RMS-norm; var partials ----
    const int d  = t & 255;
    const int rh = t >> 8;            // 0,1 -> rows {0,1} / {2,3}
    const int R0 = 2 * rh, R1 = 2 * rh + 1;
    const float* rTp = recT + d * R_;
    float bnd0 = 0.f, bnd1 = 0.f;
    #pragma unroll 4
    for (int rr = 0; rr < R_; rr += 4) {
        float4 rc = *(const float4*)(rTp + rr);
        float4 v0 = *(const float4*)&bind_lds[R0][rr];
        float4 v1 = *(const float4*)&bind_lds[R1][rr];
        bnd0 = fmaf(rc.x, v0.x, fmaf(rc.y, v0.y, fmaf(rc.z, v0.z, fmaf(rc.w, v0.w, bnd0))));
        bnd1 = fmaf(rc.x, v1.x, fmaf(rc.y, v1.y, fmaf(rc.z, v1.z, fmaf(rc.w, v1.w, bnd1))));
    }
    float x0 = keys[(rowg + R0) * D_ + d] + bnd0;
    float x1 = keys[(rowg + R1) * D_ + d] + bnd1;
    float xs0 = x0 * x0, xs1 = x1 * x1;
    #pragma unroll
    for (int o = 32; o > 0; o >>= 1) {
        xs0 += __shfl_xor(xs0, o, 64);
        xs1 += __shfl_xor(xs1, o, 64);
    }
    if (lane == 0) { redX[R0][w] = xs0; redX[R1][w] = xs1; }
    __syncthreads();
    const float scl = scalep[0];
    const int wb = rh * 4;
    float vs = 0.f, vq = 0.f;
    {
        float ms = (redX[R0][wb] + redX[R0][wb + 1] + redX[R0][wb + 2] + redX[R0][wb + 3]) * (1.0f / D_);
        float rs = scl * rsqrtf(ms + 1e-8f);
        float st = x0 * rs;
        out[(rowg + R0) * D_ + d] = st;
        vs += st; vq += st * st;
    }
    {
        float ms = (redX[R1][wb] + redX[R1][wb + 1] + redX[R1][wb + 2] + redX[R1][wb + 3]) * (1.0f / D_);
        float rs = scl * rsqrtf(ms + 1e-8f);
        float st = x1 * rs;
        out[(rowg + R1) * D_ + d] = st;
        vs += st; vq += st * st;
    }
    #pragma unroll
    for (int o = 32; o > 0; o >>= 1) {
        vs += __shfl_xor(vs, o, 64);
        vq += __shfl_xor(vq, o, 64);
    }
    if (lane == 0) { redV[0][w] = vs; redV[1][w] = vq; }
    __syncthreads();
    if (t == 0) {
        float v2s = 0.f, v2q = 0.f;
        #pragma unroll
        for (int i = 0; i < 8; i++) { v2s += redV[0][i]; v2q += redV[1][i]; }
        partials[blk * 4 + 2] = v2s;
        partials[blk * 4 + 3] = v2q;
    }
}

// K4: deterministic reduction of per-block partials -> 3 scalars
__global__ __launch_bounds__(256) void finalize(
    const float* __restrict__ partials, float* __restrict__ out)
{
    __shared__ float sh[4][4];
    const int t = threadIdx.x;
    float s0 = 0.f, s1 = 0.f, s2 = 0.f, s3 = 0.f;
    for (int k = t; k < NBLK_MAIN; k += 256) {
        s0 += partials[k * 4 + 0];
        s1 += partials[k * 4 + 1];
        s2 += partials[k * 4 + 2];
        s3 += partials[k * 4 + 3];
    }
    #pragma unroll
    for (int o = 32; o > 0; o >>= 1) {
        s0 += __shfl_xor(s0, o, 64);
        s1 += __shfl_xor(s1, o, 64);
        s2 += __shfl_xor(s2, o, 64);
        s3 += __shfl_xor(s3, o, 64);
    }
    const int w = t >> 6, lane = t & 63;
    if (lane == 0) { sh[0][w] = s0; sh[1][w] = s1; sh[2][w] = s2; sh[3][w] = s3; }
    __syncthreads();
    if (t == 0) {
        float S0 = sh[0][0] + sh[0][1] + sh[0][2] + sh[0][3];
        float S1 = sh[1][0] + sh[1][1] + sh[1][2] + sh[1][3];
        float S2 = sh[2][0] + sh[2][1] + sh[2][2] + sh[2][3];
        float S3 = sh[3][0] + sh[3][1] + sh[3][2] + sh[3][3];
        const float N = (float)(NROW * D_);
        out[NROW * D_ + 0] = S0 / (float)NROW;
        out[NROW * D_ + 1] = -S1 / (float)NROW;
        out[NROW * D_ + 2] = (S3 - S2 * S2 / N) / (N - 1.0f);
    }
}

extern "C" void kernel_launch(void* const* d_in, const int* in_sizes, int n_in,
                              void* d_out, int out_size, void* d_ws, size_t ws_size,
                              hipStream_t stream) {
    const float* keys      = (const float*)d_in[0];
    const float* receptors = (const float*)d_in[1];
    const float* W1        = (const float*)d_in[2];
    const float* b1        = (const float*)d_in[3];
    const float* W2        = (const float*)d_in[4];
    const float* b2        = (const float*)d_in[5];
    const float* oscale    = (const float*)d_in[6];
    float* out = (float*)d_out;
    char* ws   = (char*)d_ws;

    uint2* hrbq     = (uint2*)ws;                      // 64 KB
    uint2* hkq      = (uint2*)(ws + 65536);            // 2 MB
    float* recT     = (float*)(ws + 65536 + 2097152);  // 128 KB
    float* partials = (float*)(ws + 65536 + 2097152 + 131072);

    hrb_kernel<<<dim3(R_), dim3(D_), 0, stream>>>(receptors, W1, b1, hrbq, recT);
    hk_gemm<<<dim3(256), dim3(256), 0, stream>>>(keys, W1, hkq);
    main_kernel<<<dim3(NBLK_MAIN), dim3(512), 0, stream>>>(
        keys, recT, W2, b2, oscale, hkq, hrbq, out, partials);
    finalize<<<dim3(1), dim3(256), 0, stream>>>(partials, out);
}